// Round 11
// baseline (174.495 us; speedup 1.0000x reference)
//
#include <hip/hip_runtime.h>

typedef _Float16 half8 __attribute__((ext_vector_type(8)));
typedef float floatx4 __attribute__((ext_vector_type(4)));

#define BB 8
#define CC 64
#define HH 128
#define WW 256
#define DD 64
#define NROW 4            // (b,h) rows per block
#define GRID 256          // 1 block per CU; NROW*GRID == BB*HH
#define OPITCH 260        // Ob row pitch (floats): bank=(4d+w)&31 -> 2 lanes/bank

// LDS-only barrier: all cross-wave data flows through LDS; lgkmcnt(0) is
// sufficient. Prefetch loads and output stores stay in flight across
// barriers; waits are per-thread counted vmcnt at the consuming cvt.
#define BAR() asm volatile("s_waitcnt lgkmcnt(0)\n\ts_barrier" ::: "memory")

// out[b,d,h,w] = (1/64) sum_c L[b,c,h,w] * R[b,c,h,w-d], 0 where w<d.
// Banded Gram via mfma_f32_16x16x32_f16 (d = 64-16u+n-m algebra).
// R11 (58.3us): NROW=4 pipeline, lgkm-only barriers, NT stores.
// R12 (2-deep prefetch): null. R13 (per-block h-walk): regressed — per-phase
//     footprint concentration (32MB b-slice) must be preserved.
// R14 (4-point issue smoothing): null. Accounting: ~2us of CU work per
//     14.7us row; the chip-wide delivery rate is pinned at ~2.3 TB/s for
//     every per-CU scheduling variant -> the cap is the memory system's
//     rate for THIS miss pattern.
// R15: XCD-contiguous-h remap. Identity mapping gives XCD x (bid%8==x)
//     blocks with h ∈ {x, x+8, ...}: each XCD's miss stream per 128KB
//     c-plane is 16 isolated 1KB islands 8KB apart (DRAM row thrash).
//     Remap bh0 = (bid>>7)*128 + (bid&7)*16 + ((bid>>3)&15): XCD x covers
//     h ∈ [16x,16x+16) -> per-plane miss stream becomes one 16KB
//     sequential run. Bijective; per-phase address set IDENTICAL to R14
//     (only the within-phase block->row assignment changes).
__global__ __launch_bounds__(512, 2)
void corr_volume_mfma(const float* __restrict__ left,
                      const float* __restrict__ right,
                      float* __restrict__ out) {
    // 72 KiB arena: phase 1 = Lb[256*64] (32K) + Rb[320*64] (40K) halves;
    // phase 2 (epilogue) overlays Ob[64][OPITCH] floats (66,560 B).
    __shared__ alignas(16) unsigned char smem[73728];
    _Float16* const Lb = (_Float16*)smem;
    _Float16* const Rb = (_Float16*)(smem + 32768);
    float*    const Ob = (float*)smem;

    const int tid  = threadIdx.x;
    const int lane = tid & 63;
    const int wv   = tid >> 6;          // wave 0..7
    const int sw   = lane * 4;          // staged w rows sw..sw+3
    const int cg   = wv;                // staged channel group cg*8..cg*8+7

    // XCD-contiguous-h bijection on [0,256).
    const int bh0 = ((int)blockIdx.x >> 7) * 128
                  + ((int)blockIdx.x & 7) * 16
                  + (((int)blockIdx.x >> 3) & 15);

    const size_t chanStride = (size_t)HH * WW;      // 32768

    float4 lv[8], rv[8];

    // Prologue: issue row-0 loads immediately.
    {
        const int bh = bh0;
        const size_t rowBase = (size_t)(bh >> 7) * CC * chanStride
                             + (size_t)(bh & 127) * WW;
        const float* lp = left  + rowBase + (size_t)(cg * 8) * chanStride + sw;
        const float* rp = right + rowBase + (size_t)(cg * 8) * chanStride + sw;
        #pragma unroll
        for (int c = 0; c < 8; ++c) {
            lv[c] = *(const float4*)(lp + (size_t)c * chanStride);
            rv[c] = *(const float4*)(rp + (size_t)c * chanStride);
        }
    }

    const int n = lane & 15;            // MFMA col (w) / A row
    const int q = lane >> 4;            // quad
    const int wbase = wv * 32;          // this wave's w range
    const float scale = 1.0f / 64.0f;

    #pragma unroll
    for (int k = 0; k < NROW; ++k) {
        const int bh = bh0 + k * GRID;
        const int b  = bh >> 7;
        const int h  = bh & 127;

        BAR();   // A: prior row's Ob ds_reads done (k=0: orders nothing)

        // Re-zero the w'<0 pad rows (Ob overlay clobbers them every row).
        {
            half8 z = {0, 0, 0, 0, 0, 0, 0, 0};
            *(half8*)&Rb[tid * 8] = z;
        }

        // Transpose 8c x 4w from regs -> LDS. Per-thread counted vmcnt
        // waits for this row's loads happen here; no cross-wave drain.
        {
            const float* lf = (const float*)lv;
            const float* rf = (const float*)rv;
            #pragma unroll
            for (int s = 0; s < 4; ++s) {
                const int w   = sw + s;
                const int col = (cg ^ (w & 7)) * 8;
                half8 lh, rh;
                #pragma unroll
                for (int c = 0; c < 8; ++c) {
                    lh[c] = (_Float16)lf[c * 4 + s];
                    rh[c] = (_Float16)rf[c * 4 + s];
                }
                *(half8*)&Lb[w * 64 + col]        = lh;
                *(half8*)&Rb[(w + 64) * 64 + col] = rh;
            }
        }

        // Refill, group 1 of 4 (L chunks 0-3) — regs just freed by cvt.
        const float* lp2 = nullptr;
        const float* rp2 = nullptr;
        if (k + 1 < NROW) {
            const int bh2 = bh0 + (k + 1) * GRID;
            const size_t rowBase2 = (size_t)(bh2 >> 7) * CC * chanStride
                                  + (size_t)(bh2 & 127) * WW;
            lp2 = left  + rowBase2 + (size_t)(cg * 8) * chanStride + sw;
            rp2 = right + rowBase2 + (size_t)(cg * 8) * chanStride + sw;
            #pragma unroll
            for (int c = 0; c < 4; ++c)
                lv[c] = *(const float4*)(lp2 + (size_t)c * chanStride);
        }

        BAR();   // B: tiles staged (lgkmcnt-only; loads stay in flight)

        // Refill, group 2 of 4 (L chunks 4-7).
        if (k + 1 < NROW) {
            #pragma unroll
            for (int c = 4; c < 8; ++c)
                lv[c] = *(const float4*)(lp2 + (size_t)c * chanStride);
        }

        // ---------------- MFMA ----------------
        floatx4 acc[2][5];
        #pragma unroll
        for (int t = 0; t < 2; ++t)
            #pragma unroll
            for (int u = 0; u < 5; ++u)
                #pragma unroll
                for (int r = 0; r < 4; ++r)
                    acc[t][u][r] = 0.0f;

        #pragma unroll
        for (int kk = 0; kk < 2; ++kk) {
            const int col = ((kk * 4 + q) ^ (n & 7)) * 8;
            half8 bfrag[2], afrag[6];
            #pragma unroll
            for (int t = 0; t < 2; ++t)
                bfrag[t] = *(const half8*)&Lb[(wbase + t * 16 + n) * 64 + col];
            #pragma unroll
            for (int a = 0; a < 6; ++a)
                afrag[a] = *(const half8*)&Rb[(wbase + a * 16 + n) * 64 + col];
            #pragma unroll
            for (int t = 0; t < 2; ++t)
                #pragma unroll
                for (int u = 0; u < 5; ++u)
                    acc[t][u] = __builtin_amdgcn_mfma_f32_16x16x32_f16(
                        afrag[t + u], bfrag[t], acc[t][u], 0, 0, 0);

            // Refill, group 3 of 4 (R chunks 0-3) — between MFMA halves.
            if (kk == 0 && k + 1 < NROW) {
                #pragma unroll
                for (int c = 0; c < 4; ++c)
                    rv[c] = *(const float4*)(rp2 + (size_t)c * chanStride);
            }
        }
        BAR();   // C: all waves' fragment reads done; Lb/Rb dead

        // Refill, group 4 of 4 (R chunks 4-7).
        if (k + 1 < NROW) {
            #pragma unroll
            for (int c = 4; c < 8; ++c)
                rv[c] = *(const float4*)(rp2 + (size_t)c * chanStride);
        }

        // acc -> Ob[d][w]. C/D: col = n (w), row m = q*4+r. d = 64-16u+n-m.
        // bank = (4d+w)&31: all 32 banks, 2 lanes each.
        #pragma unroll
        for (int t = 0; t < 2; ++t) {
            const int w = wbase + t * 16 + n;
            #pragma unroll
            for (int u = 0; u < 5; ++u) {
                #pragma unroll
                for (int r = 0; r < 4; ++r) {
                    const int d = 64 - 16 * u + n - (q * 4 + r);
                    if (d >= 0 && d < DD) {
                        Ob[d * OPITCH + w] = acc[t][u][r] * scale;
                    }
                }
            }
        }
        BAR();   // D: Ob complete (lgkmcnt-only)

        // Coalesced nontemporal stores: wave wv owns d = wv*8..wv*8+7; each
        // instruction writes one full 1KB row. Stores drain lazily under
        // the next row's phases.
        #pragma unroll
        for (int i = 0; i < 8; ++i) {
            const int d = wv * 8 + i;
            const floatx4 v = *(const floatx4*)&Ob[d * OPITCH + lane * 4];
            floatx4* dst = (floatx4*)&out[(((size_t)b * DD + d) * HH + h) * WW + lane * 4];
            __builtin_nontemporal_store(v, dst);
        }
    }
}

extern "C" void kernel_launch(void* const* d_in, const int* in_sizes, int n_in,
                              void* d_out, int out_size, void* d_ws, size_t ws_size,
                              hipStream_t stream) {
    const float* left  = (const float*)d_in[0];
    const float* right = (const float*)d_in[1];
    float* out = (float*)d_out;

    dim3 grid(GRID);    // 256 blocks = 1 per CU, each pipelines NROW rows
    dim3 block(512);
    corr_volume_mfma<<<grid, block, 0, stream>>>(left, right, out);
}

// Round 12
// 171.548 us; speedup vs baseline: 1.0172x; 1.0172x over previous
//
#include <hip/hip_runtime.h>

typedef _Float16 half8 __attribute__((ext_vector_type(8)));
typedef _Float16 half4_t __attribute__((ext_vector_type(4)));
typedef float floatx4 __attribute__((ext_vector_type(4)));

#define BB 8
#define CC 64
#define HH 128
#define WW 256
#define DD 64
#define NROW 4            // phases per block
#define GRID 256          // 1 block per CU
#define OPITCH 260        // Ob pitch (floats)

// LDS-only barrier (R10): lgkmcnt(0)+s_barrier; vmcnt loads/stores stay in
// flight across barriers, waited per-thread (counted) at the consuming cvt.
#define BAR() asm volatile("s_waitcnt lgkmcnt(0)\n\ts_barrier" ::: "memory")

// out[b,d,h,w] = (1/64) sum_c L[b,c,h,w] * R[b,c,h,w-d], 0 where w<d.
// Banded Gram via mfma_f32_16x16x32_f16 (d = 64-16u+n-m algebra).
// R11-R15 summary: every CU-side lever (blocks/CU, outstanding bytes,
//   lgkm-only barriers, issue smoothing, 2 h-remaps) leaves delivery at
//   ~2.3 TB/s -> cap is below the CUs.
// R16: HBM-channel spread. addr = b*8MB + c*128KB + h*1KB + 4w: the c-term
//   aliases to 0 mod any pow2 channel count x plausible interleave, so a
//   block's ENTIRE 128KB burst lands on the 1-4 channels selected by its
//   single h; ~8 blocks share those channels -> ~70 GB/s demand vs ~50
//   available per channel = channel-queue saturation (explains all nulls).
//   Now each block handles TWO w-half tasks of distant rows:
//   (hA, w<128) + (hB=hA^64, w>=128) -> burst spans 2x the channels.
//   Waves 0-3 own half A, waves 4-7 half B; per-half Lb[128][64],
//   Rb[192][64] (w' = W0-64+j, half-A rows j<64 zero-padded); same band
//   algebra in local coords. Stores: 512B segments, 2 per instr.
__global__ __launch_bounds__(512, 2)
void corr_volume_mfma(const float* __restrict__ left,
                      const float* __restrict__ right,
                      float* __restrict__ out) {
    // Lb [2][128][64] f16 = 32 KB; Rb [2][192][64] f16 = 48 KB; 80 KB total.
    // Epilogue overlays Ob[64][OPITCH] f32 = 66,560 B on the dead Lb/Rb.
    __shared__ alignas(16) unsigned char smem[81920];
    _Float16* const Lb = (_Float16*)smem;            // + hf*8192
    _Float16* const Rb = (_Float16*)(smem + 32768);  // + hf*12288
    float*    const Ob = (float*)smem;

    const int tid  = threadIdx.x;
    const int lane = tid & 63;
    const int wv   = tid >> 6;          // wave 0..7

    // staging role: threads 0-255 stage half A, 256-511 half B
    const int hf  = tid >> 8;           // staged half
    const int st  = tid & 255;
    const int cg  = st >> 5;            // channel group of 8 (L, R main)
    const int wq  = (st & 31) * 4;      // local w quad 0..124
    const int cg4 = st >> 4;            // channel group of 4 (R extra)
    const int wq4 = (st & 15) * 4;      // w' quad 0..60

    const size_t chanStride = (size_t)HH * WW;      // 32768

    const int hA = blockIdx.x & 127;
    const int hB = hA ^ 64;             // distant row -> different channels
    const int hS = hf ? hB : hA;        // this thread's staged row
    const int W0 = hf << 7;             // staged w base

    float4 lv[8], rv[8], rx[4];

    // Prologue: issue phase-0 loads.
    {
        const int b0 = blockIdx.x >> 7;
        const size_t rowBase = (size_t)b0 * CC * chanStride + (size_t)hS * WW;
        const float* lp = left  + rowBase + (size_t)(cg * 8) * chanStride + W0 + wq;
        const float* rp = right + rowBase + (size_t)(cg * 8) * chanStride + W0 + wq;
        #pragma unroll
        for (int c = 0; c < 8; ++c) {
            lv[c] = *(const float4*)(lp + (size_t)c * chanStride);
            rv[c] = *(const float4*)(rp + (size_t)c * chanStride);
        }
        if (hf) {   // R extra: w' in [64,128) of hB
            const float* rq = right + rowBase + (size_t)(cg4 * 4) * chanStride + 64 + wq4;
            #pragma unroll
            for (int c = 0; c < 4; ++c)
                rx[c] = *(const float4*)(rq + (size_t)c * chanStride);
        }
    }

    // MFMA role: wave wv owns half hfw, local w range [wb, wb+32)
    const int n   = lane & 15;
    const int q   = lane >> 4;
    const int hfw = wv >> 2;
    const int wb  = (wv & 3) * 32;
    _Float16* const Lh = Lb + hfw * (128 * 64);
    _Float16* const Rh = Rb + hfw * (192 * 64);
    const int hOut = hfw ? hB : hA;
    const int W0w  = hfw << 7;
    const float scale = 1.0f / 64.0f;

    #pragma unroll
    for (int k = 0; k < NROW; ++k) {
        const int b = (blockIdx.x >> 7) + 2 * k;    // bh = bid + k*GRID

        BAR();   // A: prior phase's Ob ds_reads done

        // Zero half-A pad rows j<64 (w'<0); 512 thr x 16B = exactly 8 KB.
        {
            half8 z = {0, 0, 0, 0, 0, 0, 0, 0};
            *(half8*)&Rb[tid * 8] = z;
        }

        // Stage regs -> LDS (counted vmcnt wait lands here, per-thread).
        {
            const float* lf = (const float*)lv;
            const float* rf = (const float*)rv;
            #pragma unroll
            for (int s = 0; s < 4; ++s) {
                const int wl   = wq + s;                 // L row (local w)
                const int colL = (cg ^ (wl & 7)) * 8;
                const int j    = 64 + wl;                // R main row
                const int colR = (cg ^ (j & 7)) * 8;
                half8 lh, rh;
                #pragma unroll
                for (int c = 0; c < 8; ++c) {
                    lh[c] = (_Float16)lf[c * 4 + s];
                    rh[c] = (_Float16)rf[c * 4 + s];
                }
                *(half8*)&Lb[hf * 8192  + wl * 64 + colL] = lh;
                *(half8*)&Rb[hf * 12288 + j  * 64 + colR] = rh;
            }
            if (hf) {
                const float* rg = (const float*)rx;
                #pragma unroll
                for (int s = 0; s < 4; ++s) {
                    const int j  = wq4 + s;              // rows 0..63 half B
                    const int cb = ((cg4 >> 1) ^ (j & 7)) * 8 + (cg4 & 1) * 4;
                    half4_t v;
                    #pragma unroll
                    for (int c = 0; c < 4; ++c) v[c] = (_Float16)rg[c * 4 + s];
                    *(half4_t*)&Rb[12288 + j * 64 + cb] = v;
                }
            }
        }

        // Refill group 1 (L chunks 0-3) — regs freed by cvt above.
        const float *lp2 = nullptr, *rp2 = nullptr, *rq2 = nullptr;
        if (k + 1 < NROW) {
            const int b2 = (blockIdx.x >> 7) + 2 * (k + 1);
            const size_t rowBase2 = (size_t)b2 * CC * chanStride + (size_t)hS * WW;
            lp2 = left  + rowBase2 + (size_t)(cg * 8) * chanStride + W0 + wq;
            rp2 = right + rowBase2 + (size_t)(cg * 8) * chanStride + W0 + wq;
            rq2 = right + rowBase2 + (size_t)(cg4 * 4) * chanStride + 64 + wq4;
            #pragma unroll
            for (int c = 0; c < 4; ++c)
                lv[c] = *(const float4*)(lp2 + (size_t)c * chanStride);
        }

        BAR();   // B: tiles staged (lgkmcnt-only; loads stay in flight)

        // Refill group 2 (L chunks 4-7).
        if (k + 1 < NROW) {
            #pragma unroll
            for (int c = 4; c < 8; ++c)
                lv[c] = *(const float4*)(lp2 + (size_t)c * chanStride);
        }

        // ---------------- MFMA (local coords; w' = W0-64+j) ----------
        floatx4 acc[2][5];
        #pragma unroll
        for (int t = 0; t < 2; ++t)
            #pragma unroll
            for (int u = 0; u < 5; ++u)
                #pragma unroll
                for (int r = 0; r < 4; ++r)
                    acc[t][u][r] = 0.0f;

        #pragma unroll
        for (int kk = 0; kk < 2; ++kk) {
            const int col = ((kk * 4 + q) ^ (n & 7)) * 8;
            half8 bfrag[2], afrag[6];
            #pragma unroll
            for (int t = 0; t < 2; ++t)
                bfrag[t] = *(const half8*)&Lh[(wb + t * 16 + n) * 64 + col];
            #pragma unroll
            for (int a = 0; a < 6; ++a)
                afrag[a] = *(const half8*)&Rh[(wb + a * 16 + n) * 64 + col];
            #pragma unroll
            for (int t = 0; t < 2; ++t)
                #pragma unroll
                for (int u = 0; u < 5; ++u)
                    acc[t][u] = __builtin_amdgcn_mfma_f32_16x16x32_f16(
                        afrag[t + u], bfrag[t], acc[t][u], 0, 0, 0);

            // Refill group 3 (R chunks 0-3) — between MFMA halves.
            if (kk == 0 && k + 1 < NROW) {
                #pragma unroll
                for (int c = 0; c < 4; ++c)
                    rv[c] = *(const float4*)(rp2 + (size_t)c * chanStride);
            }
        }
        BAR();   // C: fragment reads done; Lb/Rb dead -> Ob overlay

        // Refill group 4 (R chunks 4-7 + R extra).
        if (k + 1 < NROW) {
            #pragma unroll
            for (int c = 4; c < 8; ++c)
                rv[c] = *(const float4*)(rp2 + (size_t)c * chanStride);
            if (hf) {
                #pragma unroll
                for (int c = 0; c < 4; ++c)
                    rx[c] = *(const float4*)(rq2 + (size_t)c * chanStride);
            }
        }

        // acc -> Ob[d][w_global]; d = 64-16u+n-m, m = q*4+r. Halves write
        // disjoint w ranges.
        #pragma unroll
        for (int t = 0; t < 2; ++t) {
            const int w = W0w + wb + t * 16 + n;
            #pragma unroll
            for (int u = 0; u < 5; ++u) {
                #pragma unroll
                for (int r = 0; r < 4; ++r) {
                    const int d = 64 - 16 * u + n - (q * 4 + r);
                    if (d >= 0 && d < DD) {
                        Ob[d * OPITCH + w] = acc[t][u][r] * scale;
                    }
                }
            }
        }
        BAR();   // D: Ob complete (lgkmcnt-only)

        // Stores: wave wv stores its half's w-range for 16 d-rows.
        // Each instr: 2 segments of 512 B (lanes 0-31 -> d, 32-63 -> d+1).
        #pragma unroll
        for (int i = 0; i < 8; ++i) {
            const int d = (wv & 3) * 16 + i * 2 + (lane >> 5);
            const int w = W0w + (lane & 31) * 4;
            const floatx4 v = *(const floatx4*)&Ob[d * OPITCH + w];
            floatx4* dst = (floatx4*)&out[(((size_t)b * DD + d) * HH + hOut) * WW + w];
            __builtin_nontemporal_store(v, dst);
        }
    }
}

extern "C" void kernel_launch(void* const* d_in, const int* in_sizes, int n_in,
                              void* d_out, int out_size, void* d_ws, size_t ws_size,
                              hipStream_t stream) {
    const float* left  = (const float*)d_in[0];
    const float* right = (const float*)d_in[1];
    float* out = (float*)d_out;

    dim3 grid(GRID);    // 256 blocks = 1 per CU, each pipelines NROW phases
    dim3 block(512);
    corr_volume_mfma<<<grid, block, 0, stream>>>(left, right, out);
}